// Round 6
// baseline (208.533 us; speedup 1.0000x reference)
//
#include <hip/hip_runtime.h>

#define NHEADS 12
#define HH 56
#define WW 56
#define NN (HH * WW)
#define BB 8
#define CC 384
#define RB 8              // rows per band
#define NBANDS (HH / RB)  // 7
#define LROWS (RB + 4)    // 12 staged rows (band + ±2 halo)
#define GCH 8             // channels per LDS group
#define NG 4              // channel groups (4*8 = 32 = head_dim)
#define NPAIR 224         // pixel pairs per block (8 rows * 28 pairs)
#define PLANE (LROWS * WW)       // 672 floats per staged channel
#define SLOTS (GCH * PLANE / 4)  // 1344 float4 staging slots
#define SCALE 0.17677669529663689f

// Block = 256 threads, 1 block = (b, head, 8-row band). Channels looped in 4
// groups of 8: stage k-band (12x56x8ch = 21.5KB) to LDS with linear float4
// copies (sequential 2.7KB runs per channel from HBM), accumulate 9-tap
// logits in registers across groups; softmax thread-local; then 4 v-group
// passes for PV + store. Each global line fetched once per block; all tap
// re-reads hit LDS. Thread owns 2 adjacent pixels (float2 LDS taps, 8B-aligned
// since x0, dx, row-stride all even).
__global__ __launch_bounds__(256) void dilate_attn_kernel(
    const float* __restrict__ q,
    const float* __restrict__ k,
    const float* __restrict__ v,
    float* __restrict__ out)
{
    const int tid = threadIdx.x;
    const int band = blockIdx.x;          // 0..6
    const int bh = blockIdx.y;            // 0..95
    const int b = bh / NHEADS;
    const int head = bh - b * NHEADS;
    const int y0 = band * RB;

    __shared__ float lds[GCH * PLANE + 4];   // 21520 B

    const bool act = (tid < NPAIR);

    // --- staging precompute: slot -> global element offset (row-clamped) ---
    int gOff[6];
    if (act) {
#pragma unroll
        for (int r = 0; r < 6; ++r) {
            const int slot = tid + NPAIR * r;        // 0..1343
            const int c = slot / 168;                // channel within group
            const int dw = (slot - c * 168) * 4;     // dword within channel
            const int rowp = dw / WW;                // 0..11
            const int col = dw - rowp * WW;          // multiple of 4
            const int gy = min(max(y0 - 2 + rowp, 0), HH - 1);
            gOff[r] = c * NN + gy * WW + col;
        }
    }

    // --- pixel mapping: thread -> 2 adjacent pixels ---
    const int rowL = tid / 28;            // 0..7 (act)
    const int cp = tid - rowL * 28;
    const int x0 = 2 * cp;                // even
    const int gy_pix = y0 + rowL;
    const int n = gy_pix * WW + x0;

    // --- tap geometry: LDS offsets (clamped) + per-pixel validity masks ---
    int tOff[9];
    float2 msk[9];
#pragma unroll
    for (int t = 0; t < 9; ++t) {
        const int dy = ((t / 3) - 1) * 2;
        const int dx = ((t % 3) - 1) * 2;
        const bool rowv = (unsigned)(gy_pix + dy) < HH;
        const float m0 = (rowv && (unsigned)(x0 + dx) < WW) ? 1.f : 0.f;
        const float m1 = (rowv && (unsigned)(x0 + 1 + dx) < WW) ? 1.f : 0.f;
        const int colc = min(max(x0 + dx, 0), WW - 2);   // even
        tOff[t] = (rowL + 2 + dy) * WW + colc;
        msk[t] = make_float2(m0, m1);
    }

    const size_t bhBase = ((size_t)(b * CC + head * 32)) * NN;

    float2 lg[9];
#pragma unroll
    for (int t = 0; t < 9; ++t) lg[t] = make_float2(0.f, 0.f);

    // ================= K phases: accumulate logits =================
#pragma unroll 1
    for (int g = 0; g < NG; ++g) {
        const float* src = k + bhBase + (size_t)(g * GCH) * NN;
        float4 tmp[6];
        if (act) {
#pragma unroll
            for (int r = 0; r < 6; ++r)
                tmp[r] = *reinterpret_cast<const float4*>(src + gOff[r]);
        }
        // q fragment for this group (overlaps staging latency)
        float2 qv[GCH];
        if (act) {
            const float* qp = q + bhBase + (size_t)(g * GCH) * NN + n;
#pragma unroll
            for (int d = 0; d < GCH; ++d)
                qv[d] = *reinterpret_cast<const float2*>(qp + (size_t)d * NN);
        }
        if (act) {
#pragma unroll
            for (int r = 0; r < 6; ++r)
                *reinterpret_cast<float4*>(&lds[(tid + NPAIR * r) * 4]) = tmp[r];
        }
        __syncthreads();
        if (act) {
#pragma unroll
            for (int t = 0; t < 9; ++t) {
                const float* cell = lds + tOff[t];
                float sx = lg[t].x, sy = lg[t].y;
#pragma unroll
                for (int d = 0; d < GCH; ++d) {
                    const float2 kv = *reinterpret_cast<const float2*>(cell + d * PLANE);
                    sx = fmaf(qv[d].x, kv.x, sx);
                    sy = fmaf(qv[d].y, kv.y, sy);
                }
                lg[t] = make_float2(sx, sy);
            }
        }
        __syncthreads();
    }

    // ================= softmax (thread-local, 2 px) =================
#pragma unroll
    for (int t = 0; t < 9; ++t) {
        lg[t].x *= SCALE * msk[t].x;      // OOB logits -> 0 (zero-pad unfold)
        lg[t].y *= SCALE * msk[t].y;
    }
    float mx = lg[0].x, my = lg[0].y;
#pragma unroll
    for (int t = 1; t < 9; ++t) { mx = fmaxf(mx, lg[t].x); my = fmaxf(my, lg[t].y); }
    float sx = 0.f, sy = 0.f;
#pragma unroll
    for (int t = 0; t < 9; ++t) {
        lg[t].x = __expf(lg[t].x - mx); sx += lg[t].x;
        lg[t].y = __expf(lg[t].y - my); sy += lg[t].y;
    }
    const float ix = 1.f / sx, iy = 1.f / sy;
#pragma unroll
    for (int t = 0; t < 9; ++t) {        // lg -> PV weights (masked)
        lg[t].x *= ix * msk[t].x;
        lg[t].y *= iy * msk[t].y;
    }

    // ================= V phases: PV + store per group =================
#pragma unroll 1
    for (int g = 0; g < NG; ++g) {
        const float* src = v + bhBase + (size_t)(g * GCH) * NN;
        float4 tmp[6];
        if (act) {
#pragma unroll
            for (int r = 0; r < 6; ++r)
                tmp[r] = *reinterpret_cast<const float4*>(src + gOff[r]);
#pragma unroll
            for (int r = 0; r < 6; ++r)
                *reinterpret_cast<float4*>(&lds[(tid + NPAIR * r) * 4]) = tmp[r];
        }
        __syncthreads();
        if (act) {
            float2 acc[GCH];
#pragma unroll
            for (int d = 0; d < GCH; ++d) acc[d] = make_float2(0.f, 0.f);
#pragma unroll
            for (int t = 0; t < 9; ++t) {
                const float* cell = lds + tOff[t];
                const float wx = lg[t].x, wy = lg[t].y;
#pragma unroll
                for (int d = 0; d < GCH; ++d) {
                    const float2 vv = *reinterpret_cast<const float2*>(cell + d * PLANE);
                    acc[d].x = fmaf(wx, vv.x, acc[d].x);
                    acc[d].y = fmaf(wy, vv.y, acc[d].y);
                }
            }
            // out[b, n, head*32 + g*8 + d] for both pixels
            float* ob = out + ((size_t)b * NN + n) * CC + head * 32 + g * GCH;
            *reinterpret_cast<float4*>(ob) =
                make_float4(acc[0].x, acc[1].x, acc[2].x, acc[3].x);
            *reinterpret_cast<float4*>(ob + 4) =
                make_float4(acc[4].x, acc[5].x, acc[6].x, acc[7].x);
            *reinterpret_cast<float4*>(ob + CC) =
                make_float4(acc[0].y, acc[1].y, acc[2].y, acc[3].y);
            *reinterpret_cast<float4*>(ob + CC + 4) =
                make_float4(acc[4].y, acc[5].y, acc[6].y, acc[7].y);
        }
        __syncthreads();
    }
}

extern "C" void kernel_launch(void* const* d_in, const int* in_sizes, int n_in,
                              void* d_out, int out_size, void* d_ws, size_t ws_size,
                              hipStream_t stream) {
    const float* q = (const float*)d_in[0];
    const float* k = (const float*)d_in[1];
    const float* v = (const float*)d_in[2];
    float* out = (float*)d_out;

    dim3 block(256);
    dim3 grid(NBANDS, BB * NHEADS);   // 7 x 96 = 672 blocks
    dilate_attn_kernel<<<grid, block, 0, stream>>>(q, k, v, out);
}

// Round 7
// 189.054 us; speedup vs baseline: 1.1030x; 1.1030x over previous
//
#include <hip/hip_runtime.h>

#define NHEADS 12
#define HH 56
#define WW 56
#define NN (HH * WW)
#define BB 8
#define CC 384
#define RB 8               // rows per band
#define NB 7               // bands
#define LR 12              // staged rows (band + ±2 halo)
#define GC 8               // channels per staged group
#define PL (LR * WW)       // 672 floats per staged channel plane
#define GF (GC * PL)       // 5376 floats per staged group
#define GV4 (GF / 4)       // 1344 float4 slots
#define SCALE 0.17677669529663689f

// Block = 256 threads = (b, head, 8-row band); grid 7 x 96 = 672 blocks.
// 8 channel-group phases (4 K + 4 V), double-buffered LDS: prefetch group g+1
// into registers at phase start, ds_write after compute, ONE barrier/phase.
// Thread owns 2 adjacent pixels; output accumulated across all V phases in
// regs (float2 acc[32]) and stored once as 2x128B full lines.
__global__ __launch_bounds__(256) void dilate_attn_kernel(
    const float* __restrict__ q,
    const float* __restrict__ k,
    const float* __restrict__ v,
    float* __restrict__ out)
{
    const int tid = threadIdx.x;
    const int band = blockIdx.x;
    const int bh = blockIdx.y;
    const int b = bh / NHEADS;
    const int head = bh - b * NHEADS;
    const int y0 = band * RB;

    __shared__ float buf[2][GF];   // 43008 B

    // staging slot -> global element offset (row-clamped), 6 slots/thread
    int gOff[6];
#pragma unroll
    for (int i = 0; i < 6; ++i) {
        int s = tid + 256 * i; if (s >= GV4) s = GV4 - 1;  // use is guarded
        const int ch = s / 168;
        const int rem = s - ch * 168;
        const int lr = rem / 14;
        const int c4 = rem - lr * 14;
        const int gy = min(max(y0 - 2 + lr, 0), HH - 1);
        gOff[i] = ch * NN + gy * WW + c4 * 4;
    }

    // compute mapping: 224 active threads, 2 adjacent px each
    const bool act = tid < 224;
    const int r = tid / 28;               // 0..7 when act
    const int x0 = 2 * (tid - r * 28);
    const int gy_pix = y0 + r;
    const int n0 = gy_pix * WW + x0;

    // tap LDS offsets (clamped cols) + per-pixel validity masks
    int tOff[9];
    float2 msk[9];
#pragma unroll
    for (int t = 0; t < 9; ++t) {
        const int tr = t / 3, tc = t - 3 * tr;
        const int dy = 2 * (tr - 1), dx = 2 * (tc - 1);
        const int col = min(max(x0 + dx, 0), WW - 2);
        tOff[t] = (r + 2 * tr) * WW + col;
        const bool rowv = (unsigned)(gy_pix + dy) < HH;
        msk[t].x = (rowv && (unsigned)(x0 + dx) < WW) ? 1.f : 0.f;
        msk[t].y = (rowv && (unsigned)(x0 + 1 + dx) < WW) ? 1.f : 0.f;
    }

    const size_t base = ((size_t)(b * CC + head * 32)) * NN;

    // prologue: stage K group 0 into buf[0]
    {
        const float* src = k + base;
#pragma unroll
        for (int i = 0; i < 5; ++i) {
            const float4 t4 = *reinterpret_cast<const float4*>(src + gOff[i]);
            *reinterpret_cast<float4*>(&buf[0][4 * (tid + 256 * i)]) = t4;
        }
        if (tid < 64) {
            const float4 t4 = *reinterpret_cast<const float4*>(src + gOff[5]);
            *reinterpret_cast<float4*>(&buf[0][4 * (tid + 1280)]) = t4;
        }
    }
    __syncthreads();

    float2 lg[9];
#pragma unroll
    for (int t = 0; t < 9; ++t) lg[t] = make_float2(0.f, 0.f);

    // ================= K phases =================
#pragma unroll
    for (int g = 0; g < 4; ++g) {
        // prefetch next group (K g+1, or V group 0) into registers
        const float* nsrc = (g < 3) ? (k + base + (size_t)(g + 1) * GC * NN)
                                    : (v + base);
        float4 tmp[6];
#pragma unroll
        for (int i = 0; i < 5; ++i)
            tmp[i] = *reinterpret_cast<const float4*>(nsrc + gOff[i]);
        if (tid < 64)
            tmp[5] = *reinterpret_cast<const float4*>(nsrc + gOff[5]);

        if (act) {
            const float* qp = q + base + (size_t)g * GC * NN + n0;
            float2 qv[GC];
#pragma unroll
            for (int d = 0; d < GC; ++d)
                qv[d] = *reinterpret_cast<const float2*>(qp + (size_t)d * NN);
            const float* cb = buf[g & 1];
#pragma unroll
            for (int d = 0; d < GC; ++d) {
                const float* cell = cb + d * PL;
#pragma unroll
                for (int t = 0; t < 9; ++t) {
                    const float2 kv = *reinterpret_cast<const float2*>(cell + tOff[t]);
                    lg[t].x = fmaf(qv[d].x, kv.x, lg[t].x);
                    lg[t].y = fmaf(qv[d].y, kv.y, lg[t].y);
                }
            }
        }
        // commit prefetched group to the other buffer
        float* db = buf[(g + 1) & 1];
#pragma unroll
        for (int i = 0; i < 5; ++i)
            *reinterpret_cast<float4*>(&db[4 * (tid + 256 * i)]) = tmp[i];
        if (tid < 64)
            *reinterpret_cast<float4*>(&db[4 * (tid + 1280)]) = tmp[5];
        __syncthreads();
    }

    // ================= softmax (thread-local) =================
#pragma unroll
    for (int t = 0; t < 9; ++t) {
        lg[t].x *= SCALE * msk[t].x;    // OOB logit -> 0 (zero-pad unfold)
        lg[t].y *= SCALE * msk[t].y;
    }
    float mx = lg[0].x, my = lg[0].y;
#pragma unroll
    for (int t = 1; t < 9; ++t) { mx = fmaxf(mx, lg[t].x); my = fmaxf(my, lg[t].y); }
    float sx = 0.f, sy = 0.f;
#pragma unroll
    for (int t = 0; t < 9; ++t) {
        lg[t].x = __expf(lg[t].x - mx); sx += lg[t].x;
        lg[t].y = __expf(lg[t].y - my); sy += lg[t].y;
    }
    const float ix = 1.f / sx, iy = 1.f / sy;
#pragma unroll
    for (int t = 0; t < 9; ++t) {       // lg -> masked PV weights
        lg[t].x *= ix * msk[t].x;
        lg[t].y *= iy * msk[t].y;
    }

    // ================= V phases (acc in regs, store once) =================
    float2 acc[32];
#pragma unroll
    for (int i = 0; i < 32; ++i) acc[i] = make_float2(0.f, 0.f);

#pragma unroll
    for (int g = 0; g < 4; ++g) {
        float4 tmp[6];
        if (g < 3) {
            const float* nsrc = v + base + (size_t)(g + 1) * GC * NN;
#pragma unroll
            for (int i = 0; i < 5; ++i)
                tmp[i] = *reinterpret_cast<const float4*>(nsrc + gOff[i]);
            if (tid < 64)
                tmp[5] = *reinterpret_cast<const float4*>(nsrc + gOff[5]);
        }
        if (act) {
            const float* cb = buf[g & 1];
#pragma unroll
            for (int d = 0; d < GC; ++d) {
                const float* cell = cb + d * PL;
                float2 a = acc[g * GC + d];
#pragma unroll
                for (int t = 0; t < 9; ++t) {
                    const float2 vv = *reinterpret_cast<const float2*>(cell + tOff[t]);
                    a.x = fmaf(lg[t].x, vv.x, a.x);
                    a.y = fmaf(lg[t].y, vv.y, a.y);
                }
                acc[g * GC + d] = a;
            }
        }
        if (g < 3) {
            float* db = buf[(g + 1) & 1];
#pragma unroll
            for (int i = 0; i < 5; ++i)
                *reinterpret_cast<float4*>(&db[4 * (tid + 256 * i)]) = tmp[i];
            if (tid < 64)
                *reinterpret_cast<float4*>(&db[4 * (tid + 1280)]) = tmp[5];
            __syncthreads();
        }
    }

    // store: 2 pixels x 128 B contiguous, written exactly once
    if (act) {
        float* ob = out + ((size_t)b * NN + n0) * CC + head * 32;
#pragma unroll
        for (int c = 0; c < 32; c += 4) {
            *reinterpret_cast<float4*>(ob + c) =
                make_float4(acc[c].x, acc[c + 1].x, acc[c + 2].x, acc[c + 3].x);
            *reinterpret_cast<float4*>(ob + CC + c) =
                make_float4(acc[c].y, acc[c + 1].y, acc[c + 2].y, acc[c + 3].y);
        }
    }
}

extern "C" void kernel_launch(void* const* d_in, const int* in_sizes, int n_in,
                              void* d_out, int out_size, void* d_ws, size_t ws_size,
                              hipStream_t stream) {
    const float* q = (const float*)d_in[0];
    const float* k = (const float*)d_in[1];
    const float* v = (const float*)d_in[2];
    float* out = (float*)d_out;

    dim3 block(256);
    dim3 grid(NB, BB * NHEADS);   // 7 x 96 = 672 blocks
    dilate_attn_kernel<<<grid, block, 0, stream>>>(q, k, v, out);
}